// Round 1
// baseline (724.304 us; speedup 1.0000x reference)
//
#include <hip/hip_runtime.h>

#define NT 8192
#define DD 1024
#define HH 4096
#define EE 8

typedef __attribute__((ext_vector_type(8))) short short8;
typedef __attribute__((ext_vector_type(4))) float f32x4;

__device__ __forceinline__ unsigned short f2bf(float f) {
    unsigned int u = __float_as_uint(f);
    u += 0x7FFFu + ((u >> 16) & 1u);   // round-to-nearest-even
    return (unsigned short)(u >> 16);
}

__device__ __forceinline__ void gload_lds16(const void* g, void* l) {
    __builtin_amdgcn_global_load_lds(
        (const __attribute__((address_space(1))) unsigned int*)g,
        (__attribute__((address_space(3))) unsigned int*)l, 16, 0, 0);
}

// ---- fp32 -> bf16 convert for BOTH weight tensors in one launch ----
// 8 floats/thread: 2x float4 load, 1x 16B store (coalescing sweet spot).
__global__ __launch_bounds__(256) void cvtw_kernel(const float* __restrict__ a,
                                                   const float* __restrict__ b,
                                                   unsigned short* __restrict__ da,
                                                   unsigned short* __restrict__ db) {
    const size_t half = (size_t)EE * HH * DD;
    size_t i = ((size_t)blockIdx.x * 256 + threadIdx.x) * 8;
    const float* s; unsigned short* d;
    if (i < half) { s = a + i; d = da + i; }
    else          { s = b + (i - half); d = db + (i - half); }
    float4 v0 = ((const float4*)s)[0];
    float4 v1 = ((const float4*)s)[1];
    ushort4 o0, o1;
    o0.x = f2bf(v0.x); o0.y = f2bf(v0.y); o0.z = f2bf(v0.z); o0.w = f2bf(v0.w);
    o1.x = f2bf(v1.x); o1.y = f2bf(v1.y); o1.z = f2bf(v1.z); o1.w = f2bf(v1.w);
    ((ushort4*)d)[0] = o0;
    ((ushort4*)d)[1] = o1;
}

// ---- router: one wave per token; argmax of x @ Wr^T + br ----
__global__ __launch_bounds__(256) void router_kernel(const float* __restrict__ x,
                                                     const float* __restrict__ Wr,
                                                     const float* __restrict__ br,
                                                     int* __restrict__ counts,
                                                     int* __restrict__ tlist) {
    __shared__ float sW[EE * DD];  // 32 KB
    const int t = threadIdx.x;
    for (int i = t; i < EE * DD / 4; i += 256)
        ((float4*)sW)[i] = ((const float4*)Wr)[i];
    __syncthreads();
    const int lane = t & 63;
    const int wv = t >> 6;
    const int token = blockIdx.x * 4 + wv;
    const float* xr = x + (size_t)token * DD;
    float acc[EE];
#pragma unroll
    for (int e = 0; e < EE; e++) acc[e] = 0.f;
    for (int k = lane; k < DD; k += 64) {
        float xv = xr[k];
#pragma unroll
        for (int e = 0; e < EE; e++) acc[e] += xv * sW[e * DD + k];
    }
#pragma unroll
    for (int off = 32; off > 0; off >>= 1) {
#pragma unroll
        for (int e = 0; e < EE; e++) acc[e] += __shfl_xor(acc[e], off);
    }
    if (lane == 0) {
        int best = 0;
        float bv = acc[0] + br[0];
#pragma unroll
        for (int e = 1; e < EE; e++) {
            float v = acc[e] + br[e];
            if (v > bv) { bv = v; best = e; }   // strict > == first-max (jnp.argmax)
        }
        int pos = atomicAdd(&counts[best], 1);
        tlist[best * NT + pos] = token;
    }
}

// ---- gather x rows into expert-sorted order, fp32 -> bf16 ----
__global__ __launch_bounds__(256) void gather_kernel(const float* __restrict__ x,
                                                     const int* __restrict__ tlist,
                                                     const int* __restrict__ counts,
                                                     unsigned short* __restrict__ xg) {
    const int row = blockIdx.x * 4 + (threadIdx.x >> 6);
    const int lane = threadIdx.x & 63;
    int off[EE];
    int s = 0;
#pragma unroll
    for (int k = 0; k < EE; k++) { off[k] = s; s += counts[k]; }
    int e = 0;
#pragma unroll
    for (int k = 1; k < EE; k++)
        if (row >= off[k]) e = k;
    const int token = tlist[e * NT + row - off[e]];
    const float4* src = (const float4*)(x + (size_t)token * DD);
    ushort4* dst = (ushort4*)(xg + (size_t)row * DD);
#pragma unroll
    for (int it = 0; it < 4; it++) {
        float4 v = src[it * 64 + lane];
        ushort4 o;
        o.x = f2bf(v.x); o.y = f2bf(v.y); o.z = f2bf(v.z); o.w = f2bf(v.w);
        dst[it * 64 + lane] = o;
    }
}

// LDS layouts:
//  up  (BK=32): rows of 32 bf16 (64 B, 4 chunks); chunk k of row r at slot
//               k ^ ((r>>1)&3) -- row pairs share banks at 64 B stride.
//  down(BK=64): rows of 64 bf16 (128 B, 8 chunks); chunk k of row r at slot
//               k ^ (r&7)      -- every row aliases at 128 B stride.
// Staging writes stay LDS-linear (global_load_lds constraint); the swizzle is
// applied by permuting the per-thread GLOBAL source chunk (rule: both sides or
// neither). Both GEMMs double-buffer: stage tile k+1, compute tile k, ONE
// __syncthreads per K-step (its vmcnt/lgkm drain orders everything).

// ---- up GEMM: h = silu(xg @ Wup[e]^T + bup[e]), contiguous A, bf16 out ----
__global__ __launch_bounds__(256) void up_gemm(const unsigned short* __restrict__ xg,
                                               const unsigned short* __restrict__ Wub,
                                               const float* __restrict__ bup,
                                               const int* __restrict__ counts,
                                               unsigned short* __restrict__ hbuf) {
    const int e = blockIdx.z;
    int off_e = 0, cnt;
    {
        int s = 0;
#pragma unroll
        for (int k = 0; k < EE; k++) { if (k == e) off_e = s; s += counts[k]; }
        cnt = counts[e];
    }
    const int m0 = blockIdx.y * 128;
    if (m0 >= cnt) return;
    const int n0 = blockIdx.x * 128;
    const int t = threadIdx.x;

    __shared__ unsigned short sA[2][128 * 32];   // 2 x 8 KB
    __shared__ unsigned short sB[2][128 * 32];   // 2 x 8 KB

    const int r0 = t >> 2;                      // row within 64-row half
    const int kc = (t & 3) ^ ((r0 >> 1) & 3);   // swizzled chunk this thread fetches
    const int c1 = cnt - 1;
    int ra = m0 + r0;      if (ra > c1) ra = c1;   // clamp tail rows (masked on store)
    int rb = m0 + 64 + r0; if (rb > c1) rb = c1;
    const unsigned short* gA0 = xg + (size_t)(off_e + ra) * DD + kc * 8;
    const unsigned short* gA1 = xg + (size_t)(off_e + rb) * DD + kc * 8;
    const unsigned short* gB0 = Wub + ((size_t)e * HH + n0 + r0) * DD + kc * 8;
    const unsigned short* gB1 = Wub + ((size_t)e * HH + n0 + 64 + r0) * DD + kc * 8;

    const int lane = t & 63;
    const int wm = ((t >> 6) & 1) * 64;
    const int wn = (t >> 7) * 64;
    const int mrow = lane & 15;
    const int kq = lane >> 4;
    const int slot = (kq ^ ((mrow >> 1) & 3)) * 8;   // swizzled read slot

    f32x4 acc[4][4];
#pragma unroll
    for (int i = 0; i < 4; i++)
#pragma unroll
        for (int j = 0; j < 4; j++)
            acc[i][j] = (f32x4){0.f, 0.f, 0.f, 0.f};

    auto STAGE = [&](int buf, int kt) {
        gload_lds16(gA0 + kt, &sA[buf][t * 8]);
        gload_lds16(gA1 + kt, &sA[buf][(t + 256) * 8]);
        gload_lds16(gB0 + kt, &sB[buf][t * 8]);
        gload_lds16(gB1 + kt, &sB[buf][(t + 256) * 8]);
    };

    STAGE(0, 0);
    int cur = 0;
    for (int kt = 0; kt < DD; kt += 32) {
        __syncthreads();                       // drains stage(cur) + prior reads
        if (kt + 32 < DD) STAGE(cur ^ 1, kt + 32);
        short8 a[4], b[4];
#pragma unroll
        for (int i = 0; i < 4; i++) {
            a[i] = *(const short8*)(&sA[cur][(wm + i * 16 + mrow) * 32 + slot]);
            b[i] = *(const short8*)(&sB[cur][(wn + i * 16 + mrow) * 32 + slot]);
        }
#pragma unroll
        for (int i = 0; i < 4; i++)
#pragma unroll
            for (int j = 0; j < 4; j++)
                acc[i][j] = __builtin_amdgcn_mfma_f32_16x16x32_bf16(a[i], b[j], acc[i][j], 0, 0, 0);
        cur ^= 1;
    }

    float bias[4];
#pragma unroll
    for (int j = 0; j < 4; j++) bias[j] = bup[e * HH + n0 + wn + j * 16 + mrow];
#pragma unroll
    for (int i = 0; i < 4; i++) {
#pragma unroll
        for (int r = 0; r < 4; r++) {
            int m = m0 + wm + i * 16 + kq * 4 + r;
            if (m < cnt) {
                unsigned short* hrow = hbuf + (size_t)(off_e + m) * HH + n0 + wn + mrow;
#pragma unroll
                for (int j = 0; j < 4; j++) {
                    float v = acc[i][j][r] + bias[j];
                    v = v / (1.f + __expf(-v));   // silu
                    hrow[j * 16] = f2bf(v);
                }
            }
        }
    }
}

// ---- down GEMM: out[token] = h @ Wdown[e]^T + bdown[e], fp32 scatter-out ----
// BK=64, double-buffered: 64 KB LDS -> 2 blocks/CU, matching the 512-block grid.
__global__ __launch_bounds__(256) void down_gemm(const unsigned short* __restrict__ hbuf,
                                                 const unsigned short* __restrict__ Wdb,
                                                 const float* __restrict__ bdown,
                                                 const int* __restrict__ counts,
                                                 const int* __restrict__ tlist,
                                                 float* __restrict__ out) {
    const int e = blockIdx.z;
    int off_e = 0, cnt;
    {
        int s = 0;
#pragma unroll
        for (int k = 0; k < EE; k++) { if (k == e) off_e = s; s += counts[k]; }
        cnt = counts[e];
    }
    const int m0 = blockIdx.y * 128;
    if (m0 >= cnt) return;
    const int n0 = blockIdx.x * 128;
    const int t = threadIdx.x;

    __shared__ unsigned short sA[2][128 * 64];   // 2 x 16 KB
    __shared__ unsigned short sB[2][128 * 64];   // 2 x 16 KB

    const int r = t >> 3;          // base row 0..31 (4 passes of 32 rows)
    const int c = t & 7;           // LDS chunk slot this thread fills
    const int c1 = cnt - 1;
    const unsigned short* gA[4];
    const unsigned short* gB[4];
#pragma unroll
    for (int i = 0; i < 4; i++) {
        int row = r + 32 * i;
        int sc = c ^ (row & 7);                  // pre-swizzled global chunk
        int ra = m0 + row; if (ra > c1) ra = c1; // clamp tail rows (masked on store)
        gA[i] = hbuf + (size_t)(off_e + ra) * HH + sc * 8;
        gB[i] = Wdb + ((size_t)e * DD + n0 + row) * HH + sc * 8;
    }

    const int lane = t & 63;
    const int wm = ((t >> 6) & 1) * 64;
    const int wn = (t >> 7) * 64;
    const int mrow = lane & 15;
    const int kq = lane >> 4;

    f32x4 acc[4][4];
#pragma unroll
    for (int i = 0; i < 4; i++)
#pragma unroll
        for (int j = 0; j < 4; j++)
            acc[i][j] = (f32x4){0.f, 0.f, 0.f, 0.f};

    auto STAGE = [&](int buf, int kt) {
#pragma unroll
        for (int i = 0; i < 4; i++)
            gload_lds16(gA[i] + kt, &sA[buf][(i * 256 + t) * 8]);
#pragma unroll
        for (int i = 0; i < 4; i++)
            gload_lds16(gB[i] + kt, &sB[buf][(i * 256 + t) * 8]);
    };

    STAGE(0, 0);
    int cur = 0;
    for (int kt = 0; kt < HH; kt += 64) {
        __syncthreads();                       // drains stage(cur) + prior reads
        if (kt + 64 < HH) STAGE(cur ^ 1, kt + 64);
#pragma unroll
        for (int h = 0; h < 2; h++) {
            const int slot = (((h << 2) | kq) ^ (mrow & 7)) * 8;
            short8 a[4], b[4];
#pragma unroll
            for (int i = 0; i < 4; i++) {
                a[i] = *(const short8*)(&sA[cur][(wm + i * 16 + mrow) * 64 + slot]);
                b[i] = *(const short8*)(&sB[cur][(wn + i * 16 + mrow) * 64 + slot]);
            }
#pragma unroll
            for (int i = 0; i < 4; i++)
#pragma unroll
                for (int j = 0; j < 4; j++)
                    acc[i][j] = __builtin_amdgcn_mfma_f32_16x16x32_bf16(a[i], b[j], acc[i][j], 0, 0, 0);
        }
        cur ^= 1;
    }

    const int* tl = tlist + e * NT;
    float bias[4];
#pragma unroll
    for (int j = 0; j < 4; j++) bias[j] = bdown[e * DD + n0 + wn + j * 16 + mrow];
#pragma unroll
    for (int i = 0; i < 4; i++) {
#pragma unroll
        for (int r2 = 0; r2 < 4; r2++) {
            int m = m0 + wm + i * 16 + kq * 4 + r2;
            if (m < cnt) {
                int token = tl[m];
                float* orow = out + (size_t)token * DD + n0 + wn + mrow;
#pragma unroll
                for (int j = 0; j < 4; j++)
                    orow[j * 16] = acc[i][j][r2] + bias[j];
            }
        }
    }
}

extern "C" void kernel_launch(void* const* d_in, const int* in_sizes, int n_in,
                              void* d_out, int out_size, void* d_ws, size_t ws_size,
                              hipStream_t stream) {
    const float* x     = (const float*)d_in[0];
    const float* Wr    = (const float*)d_in[1];
    const float* br    = (const float*)d_in[2];
    const float* Wup   = (const float*)d_in[3];
    const float* bup   = (const float*)d_in[4];
    const float* Wdown = (const float*)d_in[5];
    const float* bdown = (const float*)d_in[6];
    float* out = (float*)d_out;

    char* w = (char*)d_ws;
    int* counts  = (int*)w;               w += 256;
    int* tlist   = (int*)w;               w += (size_t)EE * NT * 4;
    unsigned short* xg   = (unsigned short*)w;  w += (size_t)NT * DD * 2;
    unsigned short* hbuf = (unsigned short*)w;  w += (size_t)NT * HH * 2;
    unsigned short* Wub  = (unsigned short*)w;  w += (size_t)EE * HH * DD * 2;
    unsigned short* Wdb  = (unsigned short*)w;

    hipMemsetAsync(counts, 0, EE * sizeof(int), stream);

    cvtw_kernel<<<(2 * (size_t)EE * HH * DD) / 2048, 256, 0, stream>>>(Wup, Wdown, Wub, Wdb);
    router_kernel<<<NT / 4, 256, 0, stream>>>(x, Wr, br, counts, tlist);
    gather_kernel<<<NT / 4, 256, 0, stream>>>(x, tlist, counts, xg);

    dim3 gu(HH / 128, NT / 128, EE);
    up_gemm<<<gu, 256, 0, stream>>>(xg, Wub, bup, counts, hbuf);
    dim3 gd(DD / 128, NT / 128, EE);
    down_gemm<<<gd, 256, 0, stream>>>(hbuf, Wdb, bdown, counts, tlist, out);
}

// Round 2
// 691.876 us; speedup vs baseline: 1.0469x; 1.0469x over previous
//
#include <hip/hip_runtime.h>

#define NT 8192
#define DD 1024
#define HH 4096
#define EE 8

typedef __attribute__((ext_vector_type(8))) short short8;
typedef __attribute__((ext_vector_type(4))) float f32x4;

__device__ __forceinline__ unsigned short f2bf(float f) {
    unsigned int u = __float_as_uint(f);
    u += 0x7FFFu + ((u >> 16) & 1u);   // round-to-nearest-even
    return (unsigned short)(u >> 16);
}

__device__ __forceinline__ void gload_lds16(const void* g, void* l) {
    __builtin_amdgcn_global_load_lds(
        (const __attribute__((address_space(1))) unsigned int*)g,
        (__attribute__((address_space(3))) unsigned int*)l, 16, 0, 0);
}

// ---- fp32 -> bf16 convert for BOTH weight tensors in one launch ----
__global__ __launch_bounds__(256) void cvtw_kernel(const float* __restrict__ a,
                                                   const float* __restrict__ b,
                                                   unsigned short* __restrict__ da,
                                                   unsigned short* __restrict__ db) {
    const size_t half = (size_t)EE * HH * DD;
    size_t i = ((size_t)blockIdx.x * 256 + threadIdx.x) * 8;
    const float* s; unsigned short* d;
    if (i < half) { s = a + i; d = da + i; }
    else          { s = b + (i - half); d = db + (i - half); }
    float4 v0 = ((const float4*)s)[0];
    float4 v1 = ((const float4*)s)[1];
    ushort4 o0, o1;
    o0.x = f2bf(v0.x); o0.y = f2bf(v0.y); o0.z = f2bf(v0.z); o0.w = f2bf(v0.w);
    o1.x = f2bf(v1.x); o1.y = f2bf(v1.y); o1.z = f2bf(v1.z); o1.w = f2bf(v1.w);
    ((ushort4*)d)[0] = o0;
    ((ushort4*)d)[1] = o1;
}

// ---- router: one wave per token; argmax of x @ Wr^T + br ----
__global__ __launch_bounds__(256) void router_kernel(const float* __restrict__ x,
                                                     const float* __restrict__ Wr,
                                                     const float* __restrict__ br,
                                                     int* __restrict__ counts,
                                                     int* __restrict__ tlist) {
    __shared__ float sW[EE * DD];  // 32 KB
    const int t = threadIdx.x;
    for (int i = t; i < EE * DD / 4; i += 256)
        ((float4*)sW)[i] = ((const float4*)Wr)[i];
    __syncthreads();
    const int lane = t & 63;
    const int wv = t >> 6;
    const int token = blockIdx.x * 4 + wv;
    const float* xr = x + (size_t)token * DD;
    float acc[EE];
#pragma unroll
    for (int e = 0; e < EE; e++) acc[e] = 0.f;
    for (int k = lane; k < DD; k += 64) {
        float xv = xr[k];
#pragma unroll
        for (int e = 0; e < EE; e++) acc[e] += xv * sW[e * DD + k];
    }
#pragma unroll
    for (int off = 32; off > 0; off >>= 1) {
#pragma unroll
        for (int e = 0; e < EE; e++) acc[e] += __shfl_xor(acc[e], off);
    }
    if (lane == 0) {
        int best = 0;
        float bv = acc[0] + br[0];
#pragma unroll
        for (int e = 1; e < EE; e++) {
            float v = acc[e] + br[e];
            if (v > bv) { bv = v; best = e; }   // strict > == first-max (jnp.argmax)
        }
        int pos = atomicAdd(&counts[best], 1);
        tlist[best * NT + pos] = token;
    }
}

// ---- gather x rows into expert-sorted order, fp32 -> bf16 ----
__global__ __launch_bounds__(256) void gather_kernel(const float* __restrict__ x,
                                                     const int* __restrict__ tlist,
                                                     const int* __restrict__ counts,
                                                     unsigned short* __restrict__ xg) {
    const int row = blockIdx.x * 4 + (threadIdx.x >> 6);
    const int lane = threadIdx.x & 63;
    int off[EE];
    int s = 0;
#pragma unroll
    for (int k = 0; k < EE; k++) { off[k] = s; s += counts[k]; }
    int e = 0;
#pragma unroll
    for (int k = 1; k < EE; k++)
        if (row >= off[k]) e = k;
    const int token = tlist[e * NT + row - off[e]];
    const float4* src = (const float4*)(x + (size_t)token * DD);
    ushort4* dst = (ushort4*)(xg + (size_t)row * DD);
#pragma unroll
    for (int it = 0; it < 4; it++) {
        float4 v = src[it * 64 + lane];
        ushort4 o;
        o.x = f2bf(v.x); o.y = f2bf(v.y); o.z = f2bf(v.z); o.w = f2bf(v.w);
        dst[it * 64 + lane] = o;
    }
}

// Both GEMMs: slot-compacted grid. blockIdx.y = slot in [0, 72); each block
// decodes slot -> (expert e, row block m0) via a prefix over ceil(counts/128).
// This removes all empty blocks so the dispatch round-robin spreads WORKING
// blocks across all 256 CUs. (Previous grid's working blocks had linear ids
// = 0..63 mod 512 -> all landed on CUs 0..7 of each XCD: 64/256 CUs busy.)
//
// LDS (BK=32, double-buffered, 32 KB total): rows of 32 bf16 (64 B); logical
// chunk k of row r stored at slot k ^ ((r>>1)&3). Staging writes stay
// LDS-linear (global_load_lds constraint); the swizzle is applied by
// permuting the per-thread GLOBAL source chunk. One __syncthreads per K-step
// (its vmcnt/lgkm drain orders stage(cur) completion and read(cur^1) reuse).

#define SLOTS 72

struct SlotDec { int e, off_e, cnt, m0, ok; };

__device__ __forceinline__ SlotDec decode_slot(const int* __restrict__ counts, int slot) {
    SlotDec d; d.ok = 0; d.e = 0; d.off_e = 0; d.cnt = 0; d.m0 = 0;
    int s = 0, csum = 0;
#pragma unroll
    for (int k = 0; k < EE; k++) {
        int ck = counts[k];
        int mb = (ck + 127) >> 7;
        if (!d.ok && slot < csum + mb) {
            d.ok = 1; d.e = k; d.off_e = s; d.cnt = ck; d.m0 = (slot - csum) * 128;
        }
        s += ck; csum += mb;
    }
    return d;
}

// ---- up GEMM: h = silu(xg @ Wup[e]^T + bup[e]), contiguous A, bf16 out ----
__global__ __launch_bounds__(256) void up_gemm(const unsigned short* __restrict__ xg,
                                               const unsigned short* __restrict__ Wub,
                                               const float* __restrict__ bup,
                                               const int* __restrict__ counts,
                                               unsigned short* __restrict__ hbuf) {
    SlotDec sd = decode_slot(counts, blockIdx.y);
    if (!sd.ok) return;
    const int e = sd.e, off_e = sd.off_e, cnt = sd.cnt, m0 = sd.m0;
    const int n0 = blockIdx.x * 128;
    const int t = threadIdx.x;

    __shared__ unsigned short sA[2][128 * 32];   // 2 x 8 KB
    __shared__ unsigned short sB[2][128 * 32];   // 2 x 8 KB

    const int r0 = t >> 2;                      // row within 64-row half
    const int kc = (t & 3) ^ ((r0 >> 1) & 3);   // swizzled chunk this thread fetches
    const int c1 = cnt - 1;
    int ra = m0 + r0;      if (ra > c1) ra = c1;   // clamp tail rows (masked on store)
    int rb = m0 + 64 + r0; if (rb > c1) rb = c1;
    const unsigned short* gA0 = xg + (size_t)(off_e + ra) * DD + kc * 8;
    const unsigned short* gA1 = xg + (size_t)(off_e + rb) * DD + kc * 8;
    const unsigned short* gB0 = Wub + ((size_t)e * HH + n0 + r0) * DD + kc * 8;
    const unsigned short* gB1 = Wub + ((size_t)e * HH + n0 + 64 + r0) * DD + kc * 8;

    const int lane = t & 63;
    const int wm = ((t >> 6) & 1) * 64;
    const int wn = (t >> 7) * 64;
    const int mrow = lane & 15;
    const int kq = lane >> 4;
    const int slot = (kq ^ ((mrow >> 1) & 3)) * 8;   // swizzled read slot

    f32x4 acc[4][4];
#pragma unroll
    for (int i = 0; i < 4; i++)
#pragma unroll
        for (int j = 0; j < 4; j++)
            acc[i][j] = (f32x4){0.f, 0.f, 0.f, 0.f};

    auto STAGE = [&](int buf, int kt) {
        gload_lds16(gA0 + kt, &sA[buf][t * 8]);
        gload_lds16(gA1 + kt, &sA[buf][(t + 256) * 8]);
        gload_lds16(gB0 + kt, &sB[buf][t * 8]);
        gload_lds16(gB1 + kt, &sB[buf][(t + 256) * 8]);
    };

    STAGE(0, 0);
    int cur = 0;
    for (int kt = 0; kt < DD; kt += 32) {
        __syncthreads();                       // drains stage(cur) + prior reads
        if (kt + 32 < DD) STAGE(cur ^ 1, kt + 32);
        short8 a[4], b[4];
#pragma unroll
        for (int i = 0; i < 4; i++) {
            a[i] = *(const short8*)(&sA[cur][(wm + i * 16 + mrow) * 32 + slot]);
            b[i] = *(const short8*)(&sB[cur][(wn + i * 16 + mrow) * 32 + slot]);
        }
#pragma unroll
        for (int i = 0; i < 4; i++)
#pragma unroll
            for (int j = 0; j < 4; j++)
                acc[i][j] = __builtin_amdgcn_mfma_f32_16x16x32_bf16(a[i], b[j], acc[i][j], 0, 0, 0);
        cur ^= 1;
    }

    float bias[4];
#pragma unroll
    for (int j = 0; j < 4; j++) bias[j] = bup[e * HH + n0 + wn + j * 16 + mrow];
#pragma unroll
    for (int i = 0; i < 4; i++) {
#pragma unroll
        for (int r = 0; r < 4; r++) {
            int m = m0 + wm + i * 16 + kq * 4 + r;
            if (m < cnt) {
                unsigned short* hrow = hbuf + (size_t)(off_e + m) * HH + n0 + wn + mrow;
#pragma unroll
                for (int j = 0; j < 4; j++) {
                    float v = acc[i][j][r] + bias[j];
                    v = v / (1.f + __expf(-v));   // silu
                    hrow[j * 16] = f2bf(v);
                }
            }
        }
    }
}

// ---- down GEMM: out[token] = h @ Wdown[e]^T + bdown[e], fp32 scatter-out ----
__global__ __launch_bounds__(256) void down_gemm(const unsigned short* __restrict__ hbuf,
                                                 const unsigned short* __restrict__ Wdb,
                                                 const float* __restrict__ bdown,
                                                 const int* __restrict__ counts,
                                                 const int* __restrict__ tlist,
                                                 float* __restrict__ out) {
    SlotDec sd = decode_slot(counts, blockIdx.y);
    if (!sd.ok) return;
    const int e = sd.e, off_e = sd.off_e, cnt = sd.cnt, m0 = sd.m0;
    const int n0 = blockIdx.x * 128;
    const int t = threadIdx.x;

    __shared__ unsigned short sA[2][128 * 32];   // 2 x 8 KB
    __shared__ unsigned short sB[2][128 * 32];   // 2 x 8 KB

    const int r0 = t >> 2;
    const int kc = (t & 3) ^ ((r0 >> 1) & 3);
    const int c1 = cnt - 1;
    int ra = m0 + r0;      if (ra > c1) ra = c1;
    int rb = m0 + 64 + r0; if (rb > c1) rb = c1;
    const unsigned short* gA0 = hbuf + (size_t)(off_e + ra) * HH + kc * 8;
    const unsigned short* gA1 = hbuf + (size_t)(off_e + rb) * HH + kc * 8;
    const unsigned short* gB0 = Wdb + ((size_t)e * DD + n0 + r0) * HH + kc * 8;
    const unsigned short* gB1 = Wdb + ((size_t)e * DD + n0 + 64 + r0) * HH + kc * 8;

    const int lane = t & 63;
    const int wm = ((t >> 6) & 1) * 64;
    const int wn = (t >> 7) * 64;
    const int mrow = lane & 15;
    const int kq = lane >> 4;
    const int slot = (kq ^ ((mrow >> 1) & 3)) * 8;

    f32x4 acc[4][4];
#pragma unroll
    for (int i = 0; i < 4; i++)
#pragma unroll
        for (int j = 0; j < 4; j++)
            acc[i][j] = (f32x4){0.f, 0.f, 0.f, 0.f};

    auto STAGE = [&](int buf, int kt) {
        gload_lds16(gA0 + kt, &sA[buf][t * 8]);
        gload_lds16(gA1 + kt, &sA[buf][(t + 256) * 8]);
        gload_lds16(gB0 + kt, &sB[buf][t * 8]);
        gload_lds16(gB1 + kt, &sB[buf][(t + 256) * 8]);
    };

    STAGE(0, 0);
    int cur = 0;
    for (int kt = 0; kt < HH; kt += 32) {
        __syncthreads();                       // drains stage(cur) + prior reads
        if (kt + 32 < HH) STAGE(cur ^ 1, kt + 32);
        short8 a[4], b[4];
#pragma unroll
        for (int i = 0; i < 4; i++) {
            a[i] = *(const short8*)(&sA[cur][(wm + i * 16 + mrow) * 32 + slot]);
            b[i] = *(const short8*)(&sB[cur][(wn + i * 16 + mrow) * 32 + slot]);
        }
#pragma unroll
        for (int i = 0; i < 4; i++)
#pragma unroll
            for (int j = 0; j < 4; j++)
                acc[i][j] = __builtin_amdgcn_mfma_f32_16x16x32_bf16(a[i], b[j], acc[i][j], 0, 0, 0);
        cur ^= 1;
    }

    const int* tl = tlist + e * NT;
    float bias[4];
#pragma unroll
    for (int j = 0; j < 4; j++) bias[j] = bdown[e * DD + n0 + wn + j * 16 + mrow];
#pragma unroll
    for (int i = 0; i < 4; i++) {
#pragma unroll
        for (int r = 0; r < 4; r++) {
            int m = m0 + wm + i * 16 + kq * 4 + r;
            if (m < cnt) {
                int token = tl[m];
                float* orow = out + (size_t)token * DD + n0 + wn + mrow;
#pragma unroll
                for (int j = 0; j < 4; j++)
                    orow[j * 16] = acc[i][j][r] + bias[j];
            }
        }
    }
}

extern "C" void kernel_launch(void* const* d_in, const int* in_sizes, int n_in,
                              void* d_out, int out_size, void* d_ws, size_t ws_size,
                              hipStream_t stream) {
    const float* x     = (const float*)d_in[0];
    const float* Wr    = (const float*)d_in[1];
    const float* br    = (const float*)d_in[2];
    const float* Wup   = (const float*)d_in[3];
    const float* bup   = (const float*)d_in[4];
    const float* Wdown = (const float*)d_in[5];
    const float* bdown = (const float*)d_in[6];
    float* out = (float*)d_out;

    char* w = (char*)d_ws;
    int* counts  = (int*)w;               w += 256;
    int* tlist   = (int*)w;               w += (size_t)EE * NT * 4;
    unsigned short* xg   = (unsigned short*)w;  w += (size_t)NT * DD * 2;
    unsigned short* hbuf = (unsigned short*)w;  w += (size_t)NT * HH * 2;
    unsigned short* Wub  = (unsigned short*)w;  w += (size_t)EE * HH * DD * 2;
    unsigned short* Wdb  = (unsigned short*)w;

    hipMemsetAsync(counts, 0, EE * sizeof(int), stream);

    cvtw_kernel<<<(2 * (size_t)EE * HH * DD) / 2048, 256, 0, stream>>>(Wup, Wdown, Wub, Wdb);
    router_kernel<<<NT / 4, 256, 0, stream>>>(x, Wr, br, counts, tlist);
    gather_kernel<<<NT / 4, 256, 0, stream>>>(x, tlist, counts, xg);

    dim3 gu(HH / 128, SLOTS);
    up_gemm<<<gu, 256, 0, stream>>>(xg, Wub, bup, counts, hbuf);
    dim3 gd(DD / 128, SLOTS);
    down_gemm<<<gd, 256, 0, stream>>>(hbuf, Wdb, bdown, counts, tlist, out);
}

// Round 4
// 678.545 us; speedup vs baseline: 1.0674x; 1.0196x over previous
//
#include <hip/hip_runtime.h>

#define NT 8192
#define DD 1024
#define HH 4096
#define EE 8

typedef __attribute__((ext_vector_type(8))) short short8;
typedef __attribute__((ext_vector_type(4))) float f32x4;

__device__ __forceinline__ unsigned short f2bf(float f) {
    unsigned int u = __float_as_uint(f);
    u += 0x7FFFu + ((u >> 16) & 1u);   // round-to-nearest-even
    return (unsigned short)(u >> 16);
}

__device__ __forceinline__ void gload_lds16(const void* g, void* l) {
    __builtin_amdgcn_global_load_lds(
        (const __attribute__((address_space(1))) unsigned int*)g,
        (__attribute__((address_space(3))) unsigned int*)l, 16, 0, 0);
}

// ---- fp32 -> bf16 convert for BOTH weight tensors in one launch ----
__global__ __launch_bounds__(256) void cvtw_kernel(const float* __restrict__ a,
                                                   const float* __restrict__ b,
                                                   unsigned short* __restrict__ da,
                                                   unsigned short* __restrict__ db) {
    const size_t half = (size_t)EE * HH * DD;
    size_t i = ((size_t)blockIdx.x * 256 + threadIdx.x) * 8;
    const float* s; unsigned short* d;
    if (i < half) { s = a + i; d = da + i; }
    else          { s = b + (i - half); d = db + (i - half); }
    float4 v0 = ((const float4*)s)[0];
    float4 v1 = ((const float4*)s)[1];
    ushort4 o0, o1;
    o0.x = f2bf(v0.x); o0.y = f2bf(v0.y); o0.z = f2bf(v0.z); o0.w = f2bf(v0.w);
    o1.x = f2bf(v1.x); o1.y = f2bf(v1.y); o1.z = f2bf(v1.z); o1.w = f2bf(v1.w);
    ((ushort4*)d)[0] = o0;
    ((ushort4*)d)[1] = o1;
}

// ---- router: one wave per token; argmax of x @ Wr^T + br ----
__global__ __launch_bounds__(256) void router_kernel(const float* __restrict__ x,
                                                     const float* __restrict__ Wr,
                                                     const float* __restrict__ br,
                                                     int* __restrict__ counts,
                                                     int* __restrict__ tlist) {
    __shared__ float sW[EE * DD];  // 32 KB
    const int t = threadIdx.x;
    for (int i = t; i < EE * DD / 4; i += 256)
        ((float4*)sW)[i] = ((const float4*)Wr)[i];
    __syncthreads();
    const int lane = t & 63;
    const int wv = t >> 6;
    const int token = blockIdx.x * 4 + wv;
    const float* xr = x + (size_t)token * DD;
    float acc[EE];
#pragma unroll
    for (int e = 0; e < EE; e++) acc[e] = 0.f;
    for (int k = lane; k < DD; k += 64) {
        float xv = xr[k];
#pragma unroll
        for (int e = 0; e < EE; e++) acc[e] += xv * sW[e * DD + k];
    }
#pragma unroll
    for (int off = 32; off > 0; off >>= 1) {
#pragma unroll
        for (int e = 0; e < EE; e++) acc[e] += __shfl_xor(acc[e], off);
    }
    if (lane == 0) {
        int best = 0;
        float bv = acc[0] + br[0];
#pragma unroll
        for (int e = 1; e < EE; e++) {
            float v = acc[e] + br[e];
            if (v > bv) { bv = v; best = e; }   // strict > == first-max (jnp.argmax)
        }
        int pos = atomicAdd(&counts[best], 1);
        tlist[best * NT + pos] = token;
    }
}

// ---- gather x rows into expert-sorted order, fp32 -> bf16 ----
__global__ __launch_bounds__(256) void gather_kernel(const float* __restrict__ x,
                                                     const int* __restrict__ tlist,
                                                     const int* __restrict__ counts,
                                                     unsigned short* __restrict__ xg) {
    const int row = blockIdx.x * 4 + (threadIdx.x >> 6);
    const int lane = threadIdx.x & 63;
    int off[EE];
    int s = 0;
#pragma unroll
    for (int k = 0; k < EE; k++) { off[k] = s; s += counts[k]; }
    int e = 0;
#pragma unroll
    for (int k = 1; k < EE; k++)
        if (row >= off[k]) e = k;
    const int token = tlist[e * NT + row - off[e]];
    const float4* src = (const float4*)(x + (size_t)token * DD);
    ushort4* dst = (ushort4*)(xg + (size_t)row * DD);
#pragma unroll
    for (int it = 0; it < 4; it++) {
        float4 v = src[it * 64 + lane];
        ushort4 o;
        o.x = f2bf(v.x); o.y = f2bf(v.y); o.z = f2bf(v.z); o.w = f2bf(v.w);
        dst[it * 64 + lane] = o;
    }
}

// Slot-compacted grids. blockIdx->slot decodes (expert e, row block m0) via a
// prefix over ceil(counts/128).
//
// down_gemm uses an XCD-aware REGION map: measured FETCH_SIZE showed ~2.8x
// HBM over-fetch because a slot's 8 n-blocks (sharing the A panel) landed on
// 8 different XCDs (linear id % 8 = XCD), so A was re-fetched from L3/HBM by
// every XCD. Region = 4 slots x 8 n-blocks (32 blocks) pinned to ONE XCD's
// 32 CUs via lin = g*256 + i*8 + rm (region r = g*8+rm, member i): A-tiles
// shared 8-way and B-tiles 4-way within one L2.
// ID SPACE: g in [0,3) x i in [0,32) x rm in [0,8) = 768 ids for 18 regions;
// ids with r >= 18 early-out. (Round 3 launched 576 and silently dropped
// members of regions 16-17 -> wrong output. Grid MUST be 768.)
//
// LDS (BK=32, double-buffered, 32 KB total): rows of 32 bf16 (64 B); logical
// chunk k of row r stored at slot k ^ ((r>>1)&3). Staging writes stay
// LDS-linear (global_load_lds constraint); swizzle applied by permuting the
// per-thread GLOBAL source chunk. One __syncthreads per K-step.

#define SLOTS 72

struct SlotDec { int e, off_e, cnt, m0, ok; };

__device__ __forceinline__ SlotDec decode_slot(const int* __restrict__ counts, int slot) {
    SlotDec d; d.ok = 0; d.e = 0; d.off_e = 0; d.cnt = 0; d.m0 = 0;
    int s = 0, csum = 0;
#pragma unroll
    for (int k = 0; k < EE; k++) {
        int ck = counts[k];
        int mb = (ck + 127) >> 7;
        if (!d.ok && slot < csum + mb) {
            d.ok = 1; d.e = k; d.off_e = s; d.cnt = ck; d.m0 = (slot - csum) * 128;
        }
        s += ck; csum += mb;
    }
    return d;
}

// ---- up GEMM: h = silu(xg @ Wup[e]^T + bup[e]), contiguous A, bf16 out ----
__global__ __launch_bounds__(256) void up_gemm(const unsigned short* __restrict__ xg,
                                               const unsigned short* __restrict__ Wub,
                                               const float* __restrict__ bup,
                                               const int* __restrict__ counts,
                                               unsigned short* __restrict__ hbuf) {
    SlotDec sd = decode_slot(counts, blockIdx.y);
    if (!sd.ok) return;
    const int e = sd.e, off_e = sd.off_e, cnt = sd.cnt, m0 = sd.m0;
    const int n0 = blockIdx.x * 128;
    const int t = threadIdx.x;

    __shared__ unsigned short sA[2][128 * 32];   // 2 x 8 KB
    __shared__ unsigned short sB[2][128 * 32];   // 2 x 8 KB

    const int r0 = t >> 2;                      // row within 64-row half
    const int kc = (t & 3) ^ ((r0 >> 1) & 3);   // swizzled chunk this thread fetches
    const int c1 = cnt - 1;
    int ra = m0 + r0;      if (ra > c1) ra = c1;   // clamp tail rows (masked on store)
    int rb = m0 + 64 + r0; if (rb > c1) rb = c1;
    const unsigned short* gA0 = xg + (size_t)(off_e + ra) * DD + kc * 8;
    const unsigned short* gA1 = xg + (size_t)(off_e + rb) * DD + kc * 8;
    const unsigned short* gB0 = Wub + ((size_t)e * HH + n0 + r0) * DD + kc * 8;
    const unsigned short* gB1 = Wub + ((size_t)e * HH + n0 + 64 + r0) * DD + kc * 8;

    const int lane = t & 63;
    const int wm = ((t >> 6) & 1) * 64;
    const int wn = (t >> 7) * 64;
    const int mrow = lane & 15;
    const int kq = lane >> 4;
    const int slot = (kq ^ ((mrow >> 1) & 3)) * 8;   // swizzled read slot

    f32x4 acc[4][4];
#pragma unroll
    for (int i = 0; i < 4; i++)
#pragma unroll
        for (int j = 0; j < 4; j++)
            acc[i][j] = (f32x4){0.f, 0.f, 0.f, 0.f};

    auto STAGE = [&](int buf, int kt) {
        gload_lds16(gA0 + kt, &sA[buf][t * 8]);
        gload_lds16(gA1 + kt, &sA[buf][(t + 256) * 8]);
        gload_lds16(gB0 + kt, &sB[buf][t * 8]);
        gload_lds16(gB1 + kt, &sB[buf][(t + 256) * 8]);
    };

    STAGE(0, 0);
    int cur = 0;
    for (int kt = 0; kt < DD; kt += 32) {
        __syncthreads();                       // drains stage(cur) + prior reads
        if (kt + 32 < DD) STAGE(cur ^ 1, kt + 32);
        short8 a[4], b[4];
#pragma unroll
        for (int i = 0; i < 4; i++) {
            a[i] = *(const short8*)(&sA[cur][(wm + i * 16 + mrow) * 32 + slot]);
            b[i] = *(const short8*)(&sB[cur][(wn + i * 16 + mrow) * 32 + slot]);
        }
#pragma unroll
        for (int i = 0; i < 4; i++)
#pragma unroll
            for (int j = 0; j < 4; j++)
                acc[i][j] = __builtin_amdgcn_mfma_f32_16x16x32_bf16(a[i], b[j], acc[i][j], 0, 0, 0);
        cur ^= 1;
    }

    float bias[4];
#pragma unroll
    for (int j = 0; j < 4; j++) bias[j] = bup[e * HH + n0 + wn + j * 16 + mrow];
#pragma unroll
    for (int i = 0; i < 4; i++) {
#pragma unroll
        for (int r = 0; r < 4; r++) {
            int m = m0 + wm + i * 16 + kq * 4 + r;
            if (m < cnt) {
                unsigned short* hrow = hbuf + (size_t)(off_e + m) * HH + n0 + wn + mrow;
#pragma unroll
                for (int j = 0; j < 4; j++) {
                    float v = acc[i][j][r] + bias[j];
                    v = v / (1.f + __expf(-v));   // silu
                    hrow[j * 16] = f2bf(v);
                }
            }
        }
    }
}

// ---- down GEMM: out[token] = h @ Wdown[e]^T + bdown[e], fp32 scatter-out ----
// 1-D grid of 768; XCD-region decode (see comment above).
__global__ __launch_bounds__(256) void down_gemm(const unsigned short* __restrict__ hbuf,
                                                 const unsigned short* __restrict__ Wdb,
                                                 const float* __restrict__ bdown,
                                                 const int* __restrict__ counts,
                                                 const int* __restrict__ tlist,
                                                 float* __restrict__ out) {
    // region decode: lin = g*256 + i*8 + rm ; region r = g*8 + rm (18 regions
    // of 4 slots x 8 n-blocks); member i: slot = 4r + (i&3), nb = i>>2.
    const int lin = blockIdx.x;
    const int rm = lin & 7;
    const int g  = lin >> 8;
    const int i_ = (lin >> 3) & 31;
    const int r  = g * 8 + rm;
    if (r >= (SLOTS / 4)) return;
    const int slot_id = r * 4 + (i_ & 3);
    const int nb = i_ >> 2;

    SlotDec sd = decode_slot(counts, slot_id);
    if (!sd.ok) return;
    const int e = sd.e, off_e = sd.off_e, cnt = sd.cnt, m0 = sd.m0;
    const int n0 = nb * 128;
    const int t = threadIdx.x;

    __shared__ unsigned short sA[2][128 * 32];   // 2 x 8 KB
    __shared__ unsigned short sB[2][128 * 32];   // 2 x 8 KB

    const int r0 = t >> 2;
    const int kc = (t & 3) ^ ((r0 >> 1) & 3);
    const int c1 = cnt - 1;
    int ra = m0 + r0;      if (ra > c1) ra = c1;
    int rb = m0 + 64 + r0; if (rb > c1) rb = c1;
    const unsigned short* gA0 = hbuf + (size_t)(off_e + ra) * HH + kc * 8;
    const unsigned short* gA1 = hbuf + (size_t)(off_e + rb) * HH + kc * 8;
    const unsigned short* gB0 = Wdb + ((size_t)e * DD + n0 + r0) * HH + kc * 8;
    const unsigned short* gB1 = Wdb + ((size_t)e * DD + n0 + 64 + r0) * HH + kc * 8;

    const int lane = t & 63;
    const int wm = ((t >> 6) & 1) * 64;
    const int wn = (t >> 7) * 64;
    const int mrow = lane & 15;
    const int kq = lane >> 4;
    const int slot = (kq ^ ((mrow >> 1) & 3)) * 8;

    f32x4 acc[4][4];
#pragma unroll
    for (int i = 0; i < 4; i++)
#pragma unroll
        for (int j = 0; j < 4; j++)
            acc[i][j] = (f32x4){0.f, 0.f, 0.f, 0.f};

    auto STAGE = [&](int buf, int kt) {
        gload_lds16(gA0 + kt, &sA[buf][t * 8]);
        gload_lds16(gA1 + kt, &sA[buf][(t + 256) * 8]);
        gload_lds16(gB0 + kt, &sB[buf][t * 8]);
        gload_lds16(gB1 + kt, &sB[buf][(t + 256) * 8]);
    };

    STAGE(0, 0);
    int cur = 0;
    for (int kt = 0; kt < HH; kt += 32) {
        __syncthreads();                       // drains stage(cur) + prior reads
        if (kt + 32 < HH) STAGE(cur ^ 1, kt + 32);
        short8 a[4], b[4];
#pragma unroll
        for (int i = 0; i < 4; i++) {
            a[i] = *(const short8*)(&sA[cur][(wm + i * 16 + mrow) * 32 + slot]);
            b[i] = *(const short8*)(&sB[cur][(wn + i * 16 + mrow) * 32 + slot]);
        }
#pragma unroll
        for (int i = 0; i < 4; i++)
#pragma unroll
            for (int j = 0; j < 4; j++)
                acc[i][j] = __builtin_amdgcn_mfma_f32_16x16x32_bf16(a[i], b[j], acc[i][j], 0, 0, 0);
        cur ^= 1;
    }

    const int* tl = tlist + e * NT;
    float bias[4];
#pragma unroll
    for (int j = 0; j < 4; j++) bias[j] = bdown[e * DD + n0 + wn + j * 16 + mrow];
#pragma unroll
    for (int i = 0; i < 4; i++) {
#pragma unroll
        for (int r2 = 0; r2 < 4; r2++) {
            int m = m0 + wm + i * 16 + kq * 4 + r2;
            if (m < cnt) {
                int token = tl[m];
                float* orow = out + (size_t)token * DD + n0 + wn + mrow;
#pragma unroll
                for (int j = 0; j < 4; j++)
                    orow[j * 16] = acc[i][j][r2] + bias[j];
            }
        }
    }
}

extern "C" void kernel_launch(void* const* d_in, const int* in_sizes, int n_in,
                              void* d_out, int out_size, void* d_ws, size_t ws_size,
                              hipStream_t stream) {
    const float* x     = (const float*)d_in[0];
    const float* Wr    = (const float*)d_in[1];
    const float* br    = (const float*)d_in[2];
    const float* Wup   = (const float*)d_in[3];
    const float* bup   = (const float*)d_in[4];
    const float* Wdown = (const float*)d_in[5];
    const float* bdown = (const float*)d_in[6];
    float* out = (float*)d_out;

    char* w = (char*)d_ws;
    int* counts  = (int*)w;               w += 256;
    int* tlist   = (int*)w;               w += (size_t)EE * NT * 4;
    unsigned short* xg   = (unsigned short*)w;  w += (size_t)NT * DD * 2;
    unsigned short* hbuf = (unsigned short*)w;  w += (size_t)NT * HH * 2;
    unsigned short* Wub  = (unsigned short*)w;  w += (size_t)EE * HH * DD * 2;
    unsigned short* Wdb  = (unsigned short*)w;

    hipMemsetAsync(counts, 0, EE * sizeof(int), stream);

    cvtw_kernel<<<(2 * (size_t)EE * HH * DD) / 2048, 256, 0, stream>>>(Wup, Wdown, Wub, Wdb);
    router_kernel<<<NT / 4, 256, 0, stream>>>(x, Wr, br, counts, tlist);
    gather_kernel<<<NT / 4, 256, 0, stream>>>(x, tlist, counts, xg);

    dim3 gu(HH / 128, SLOTS);
    up_gemm<<<gu, 256, 0, stream>>>(xg, Wub, bup, counts, hbuf);
    // down: XCD-region-mapped 1-D grid: id space 3*256 = 768 (18 regions of
    // 32 blocks + early-out holes). NOT 576 — see comment at decode.
    down_gemm<<<768, 256, 0, stream>>>(hbuf, Wdb, bdown, counts, tlist, out);
}